// Round 5
// baseline (342.366 us; speedup 1.0000x reference)
//
#include <hip/hip_runtime.h>
#include <hip/hip_bf16.h>

typedef unsigned short u16;

#define M_ROWS 8192
#define N_ROWS 16384
#define KDIM   512
#define BM     128
#define BN     128
#define BK     64
#define NCHUNKS 16
#define NPER   (N_ROWS / NCHUNKS)   /* 1024 */
#define TOPK   9

typedef __attribute__((ext_vector_type(8)))  short bf16x8;
typedef __attribute__((ext_vector_type(16))) float f32x16;

__device__ __forceinline__ void gload_lds16(const void* g, void* l) {
  __builtin_amdgcn_global_load_lds(
      (const __attribute__((address_space(1))) void*)g,
      (__attribute__((address_space(3))) void*)l,
      16, 0, 0);
}

__device__ __forceinline__ u16 f2bf(float x) {
  union { float f; unsigned u; } c; c.f = x;
  unsigned u = c.u;
  u += 0x7fffu + ((u >> 16) & 1u);   // RNE; inputs finite randn
  return (u16)(u >> 16);
}

__device__ __forceinline__ void topk_update(float v, float best[TOPK]) {
  if (v < best[TOPK - 1]) {
    #pragma unroll
    for (int i = 0; i < TOPK; ++i) {
      float b = best[i];
      best[i] = fminf(b, v);
      v = fmaxf(b, v);
    }
  }
}

// ---- Kernel 1: fp32 -> bf16 convert + fp32 row norms; mb norms scattered into
//      MFMA-C-layout permuted order so the GEMM epilogue reads them as broadcasts.
__global__ __launch_bounds__(256) void prep_kernel(
    const float* __restrict__ fv, const float* __restrict__ mb,
    u16* __restrict__ fvb, u16* __restrict__ mbb,
    float* __restrict__ nf, float* __restrict__ nm_perm)
{
  int idx = blockIdx.x * 4 + (threadIdx.x >> 6);   // one wave per row
  int l = threadIdx.x & 63;
  const float* src; u16* dst;
  if (idx < M_ROWS) {
    src = fv + (size_t)idx * KDIM; dst = fvb + (size_t)idx * KDIM;
  } else {
    int r = idx - M_ROWS;
    src = mb + (size_t)r * KDIM; dst = mbb + (size_t)r * KDIM;
  }
  float4 x0 = ((const float4*)src)[2 * l];
  float4 x1 = ((const float4*)src)[2 * l + 1];
  float s = x0.x * x0.x + x0.y * x0.y + x0.z * x0.z + x0.w * x0.w
          + x1.x * x1.x + x1.y * x1.y + x1.z * x1.z + x1.w * x1.w;
  uint4 o;
  o.x = (unsigned)f2bf(x0.x) | ((unsigned)f2bf(x0.y) << 16);
  o.y = (unsigned)f2bf(x0.z) | ((unsigned)f2bf(x0.w) << 16);
  o.z = (unsigned)f2bf(x1.x) | ((unsigned)f2bf(x1.y) << 16);
  o.w = (unsigned)f2bf(x1.z) | ((unsigned)f2bf(x1.w) << 16);
  ((uint4*)dst)[l] = o;
  #pragma unroll
  for (int off = 32; off > 0; off >>= 1) s += __shfl_down(s, off, 64);
  if (l == 0) {
    if (idx < M_ROWS) {
      nf[idx] = s;
    } else {
      // 32x32 C/D: within-tile row w5 = (r&3) + 8*(r>>2) + 4*h  ->  [tile][h][r]
      int n  = idx - M_ROWS;
      int ig = n >> 5;            // global 32-row tile index (512 tiles)
      int w5 = n & 31;
      int h  = (w5 >> 2) & 1;
      int r  = (w5 & 3) | ((w5 >> 3) << 2);
      nm_perm[(ig * 2 + h) * 16 + r] = s;
    }
  }
}

// ---- Kernel 2: bf16 32x32x16 MFMA GEMM (swapped operands) + per-thread top-9 ----
// grid (64, 16), block 256 (4 waves). Block: 128 fv-rows (m) x 1024 mb-rows (n).
// Wave w owns m-strip w*32..w*32+31; lane's col m = strip + (l&31) -> ONE top-9 list.
// C[row=n][col=m]. Ranked v = nm[n] - 2*dot (nf[m] deferred to merge).
// LDS XOR-swizzle: 16B chunk c of row r stored at chunk c^(r&7) (R4: conflicts
// 5.0e7 -> 2.1e7, gemm 507 -> 239 us). R4 post-mortem: grid 512 = 2 blocks/CU was
// the occupancy binder (Occ 22%, no pipe >50%); NCHUNKS=16 -> 1024 blocks = 4/CU,
// which VGPR=120 (4 waves/SIMD) and LDS 32 KB admit.
__global__ __launch_bounds__(256) void gemm_topk_kernel(
    const u16* __restrict__ fvb, const u16* __restrict__ mbb,
    const float* __restrict__ nm_perm, float* __restrict__ partial)
{
  __shared__ __align__(16) u16 As[BM * BK];     // fv tile [128][64], 16 KB
  __shared__ __align__(16) u16 Bs[BN * BK];     // mb tile [128][64], 16 KB

  const int t   = threadIdx.x;
  const int l   = t & 63;
  const int w   = t >> 6;
  const int h   = l >> 5;        // half-wave
  const int c31 = l & 31;
  const int cx  = c31 & 7;       // frag-read row&7 (both As strip and Bs tiles)

  const int m0    = blockIdx.x * BM;
  const int ncoff = blockIdx.y * NPER;

  // staging: lane l covers row (base + l>>3), chunk l&7; source chunk swizzled
  const int srow_lo = l >> 3;                    // 0..7
  const int sc      = ((l & 7) ^ srow_lo) * 8;   // swizzled source k-offset (u16)

  float best[TOPK];
  #pragma unroll
  for (int i = 0; i < TOPK; ++i) best[i] = 3.4e38f;
  float T = 3.4e38f;

  for (int nt = 0; nt < NPER / BN; ++nt) {
    const int nbase = ncoff + nt * BN;
    f32x16 acc[4];
    #pragma unroll
    for (int i = 0; i < 4; ++i)
      #pragma unroll
      for (int r = 0; r < 16; ++r) acc[i][r] = 0.0f;

    for (int kc = 0; kc < KDIM / BK; ++kc) {
      __syncthreads();
      const int kb = kc * BK + sc;
      #pragma unroll
      for (int i = 0; i < 4; ++i) {
        gload_lds16(fvb + (size_t)(m0 + w * 32 + i * 8 + srow_lo) * KDIM + kb,
                    &As[(w * 32 + i * 8) * BK]);
        gload_lds16(mbb + (size_t)(nbase + w * 32 + i * 8 + srow_lo) * KDIM + kb,
                    &Bs[(w * 32 + i * 8) * BK]);
      }
      __syncthreads();
      #pragma unroll
      for (int kk = 0; kk < 4; ++kk) {
        const int ch = ((kk * 2 + h) ^ cx) * 8;              // swizzled chunk (u16)
        bf16x8 fvf = *(const bf16x8*)&As[(w * 32 + c31) * BK + ch];  // B-operand (m)
        #pragma unroll
        for (int i = 0; i < 4; ++i) {
          bf16x8 mbf = *(const bf16x8*)&Bs[(i * 32 + c31) * BK + ch]; // A-operand (n)
          acc[i] = __builtin_amdgcn_mfma_f32_32x32x16_bf16(mbf, fvf, acc[i], 0, 0, 0);
        }
      }
    }

    // ---- register epilogue: one list per thread; nm in permuted broadcast order ----
    #pragma unroll
    for (int i = 0; i < 4; ++i) {
      const float4* np = (const float4*)&nm_perm[(((nbase >> 5) + i) * 2 + h) * 16];
      float v[16];
      float bmin = 3.4e38f;
      #pragma unroll
      for (int rr = 0; rr < 4; ++rr) {
        float4 q = np[rr];
        v[rr * 4 + 0] = fmaf(-2.0f, acc[i][rr * 4 + 0], q.x);
        v[rr * 4 + 1] = fmaf(-2.0f, acc[i][rr * 4 + 1], q.y);
        v[rr * 4 + 2] = fmaf(-2.0f, acc[i][rr * 4 + 2], q.z);
        v[rr * 4 + 3] = fmaf(-2.0f, acc[i][rr * 4 + 3], q.w);
      }
      #pragma unroll
      for (int r = 0; r < 16; ++r) bmin = fminf(bmin, v[r]);
      if (bmin < T) {
        #pragma unroll
        for (int r = 0; r < 16; ++r) topk_update(v[r], best);
      }
    }
    T = fminf(best[TOPK - 1], __shfl_xor(best[TOPK - 1], 32, 64));
  }

  // merge the lane pair sharing this m-col (snapshot partner list, then insert)
  {
    float tmp[TOPK];
    #pragma unroll
    for (int s = 0; s < TOPK; ++s) tmp[s] = __shfl_xor(best[s], 32, 64);
    #pragma unroll
    for (int s = 0; s < TOPK; ++s) topk_update(tmp[s], best);
  }
  int m = m0 + w * 32 + c31;
  size_t base = ((size_t)blockIdx.y * M_ROWS + m) * TOPK;
  if (h == 0) {
    #pragma unroll
    for (int s = 0; s < 5; ++s) partial[base + s] = best[s];
  } else {
    #pragma unroll
    for (int s = 5; s < TOPK; ++s) partial[base + s] = best[s];
  }
}

// ---------------- Kernel 3: merge 16 partial lists/row, sqrt, pixel scores ----------------
__global__ __launch_bounds__(256) void merge_kernel(
    const float* __restrict__ partial, const float* __restrict__ nf,
    float* __restrict__ final9, float* __restrict__ out_pix)
{
  int row = blockIdx.x * 256 + threadIdx.x;   // 8192 rows
  float best[TOPK];
  #pragma unroll
  for (int i = 0; i < TOPK; ++i) best[i] = 3.4e38f;
  for (int s = 0; s < NCHUNKS; ++s) {
    const float* p = &partial[((size_t)s * M_ROWS + row) * TOPK];
    #pragma unroll
    for (int i = 0; i < TOPK; ++i) topk_update(p[i], best);
  }
  float nfr = nf[row];
  float d[TOPK];
  #pragma unroll
  for (int i = 0; i < TOPK; ++i) d[i] = sqrtf(fmaxf(best[i] + nfr, 0.0f));
  out_pix[row] = d[0];
  #pragma unroll
  for (int i = 0; i < TOPK; ++i) final9[(size_t)row * TOPK + i] = d[i];
}

// ---------------- Kernel 4: per-image argmax (first-max) + softmax score ----------------
__global__ __launch_bounds__(256) void img_kernel(
    const float* __restrict__ out_pix, const float* __restrict__ final9,
    const int* __restrict__ bptr, float* __restrict__ out_img)
{
  int img = blockIdx.x, t = threadIdx.x;
  float bv = -1.0f; int bi = 0;
  for (int p = t; p < 1024; p += 256) {
    float v = out_pix[img * 1024 + p];
    if (v > bv) { bv = v; bi = p; }
  }
  __shared__ float sv[256];
  __shared__ int   si[256];
  sv[t] = bv; si[t] = bi;
  __syncthreads();
  for (int off = 128; off > 0; off >>= 1) {
    if (t < off) {
      float v2 = sv[t + off]; int i2 = si[t + off];
      if (v2 > sv[t] || (v2 == sv[t] && i2 < si[t])) { sv[t] = v2; si[t] = i2; }
    }
    __syncthreads();
  }
  if (t == 0) {
    int row = img * 1024 + si[0];
    int b = bptr[0];
    float s0 = final9[(size_t)row * TOPK + 0];
    float score = s0;
    if (b > 1) {
      int bb = b < TOPK ? b : TOPK;
      float mx = s0;
      for (int i = 1; i < bb; ++i) mx = fmaxf(mx, final9[(size_t)row * TOPK + i]);
      float den = 0.0f;
      for (int i = 0; i < bb; ++i) den += expf(final9[(size_t)row * TOPK + i] - mx);
      score = s0 * (1.0f - expf(s0 - mx) / den);
    }
    out_img[img] = score;
  }
}

extern "C" void kernel_launch(void* const* d_in, const int* in_sizes, int n_in,
                              void* d_out, int out_size, void* d_ws, size_t ws_size,
                              hipStream_t stream) {
  const float* fv   = (const float*)d_in[0];
  const float* mb   = (const float*)d_in[1];
  const int*   bptr = (const int*)d_in[2];
  float* out = (float*)d_out;

  char* w = (char*)d_ws;
  u16*   fvb     = (u16*)w;                        // 8388608 B
  u16*   mbb     = (u16*)(w + 8388608);            // 16777216 B
  float* nf      = (float*)(w + 25165824);         // 32768 B
  float* nm_perm = (float*)(w + 25198592);         // 65536 B
  float* partial = (float*)(w + 25264128);         // 16*8192*9*4 = 4718592 B
  float* final9  = (float*)(w + 29982720);         // 294912 B   (end ~30.3 MB)

  hipLaunchKernelGGL(prep_kernel, dim3((M_ROWS + N_ROWS) / 4), dim3(256), 0, stream,
                     fv, mb, fvb, mbb, nf, nm_perm);
  hipLaunchKernelGGL(gemm_topk_kernel, dim3(M_ROWS / BM, NCHUNKS), dim3(256), 0, stream,
                     fvb, mbb, nm_perm, partial);
  hipLaunchKernelGGL(merge_kernel, dim3(M_ROWS / 256), dim3(256), 0, stream,
                     partial, nf, final9, out);
  hipLaunchKernelGGL(img_kernel, dim3(8), dim3(256), 0, stream,
                     out, final9, bptr, out + M_ROWS);
}

// Round 6
// 317.704 us; speedup vs baseline: 1.0776x; 1.0776x over previous
//
#include <hip/hip_runtime.h>
#include <hip/hip_bf16.h>

typedef unsigned short u16;

#define M_ROWS 8192
#define N_ROWS 16384
#define KDIM   512
#define BM     128
#define BN     128
#define BK     64
#define NCHUNKS 8
#define NPER   (N_ROWS / NCHUNKS)   /* 2048 */
#define NT_CNT (NPER / BN)          /* 16 */
#define TOPK   9

typedef __attribute__((ext_vector_type(8)))  short bf16x8;
typedef __attribute__((ext_vector_type(16))) float f32x16;

__device__ __forceinline__ void gload_lds16(const void* g, void* l) {
  __builtin_amdgcn_global_load_lds(
      (const __attribute__((address_space(1))) void*)g,
      (__attribute__((address_space(3))) void*)l,
      16, 0, 0);
}

__device__ __forceinline__ u16 f2bf(float x) {
  union { float f; unsigned u; } c; c.f = x;
  unsigned u = c.u;
  u += 0x7fffu + ((u >> 16) & 1u);   // RNE; inputs finite randn
  return (u16)(u >> 16);
}

__device__ __forceinline__ void topk_update(float v, float best[TOPK]) {
  if (v < best[TOPK - 1]) {
    #pragma unroll
    for (int i = 0; i < TOPK; ++i) {
      float b = best[i];
      best[i] = fminf(b, v);
      v = fmaxf(b, v);
    }
  }
}

// ---- Kernel 1: fp32 -> bf16 convert + fp32 row norms; mb norms scattered into
//      MFMA-C-layout permuted order so the GEMM epilogue reads them as broadcasts.
__global__ __launch_bounds__(256) void prep_kernel(
    const float* __restrict__ fv, const float* __restrict__ mb,
    u16* __restrict__ fvb, u16* __restrict__ mbb,
    float* __restrict__ nf, float* __restrict__ nm_perm)
{
  int idx = blockIdx.x * 4 + (threadIdx.x >> 6);   // one wave per row
  int l = threadIdx.x & 63;
  const float* src; u16* dst;
  if (idx < M_ROWS) {
    src = fv + (size_t)idx * KDIM; dst = fvb + (size_t)idx * KDIM;
  } else {
    int r = idx - M_ROWS;
    src = mb + (size_t)r * KDIM; dst = mbb + (size_t)r * KDIM;
  }
  float4 x0 = ((const float4*)src)[2 * l];
  float4 x1 = ((const float4*)src)[2 * l + 1];
  float s = x0.x * x0.x + x0.y * x0.y + x0.z * x0.z + x0.w * x0.w
          + x1.x * x1.x + x1.y * x1.y + x1.z * x1.z + x1.w * x1.w;
  uint4 o;
  o.x = (unsigned)f2bf(x0.x) | ((unsigned)f2bf(x0.y) << 16);
  o.y = (unsigned)f2bf(x0.z) | ((unsigned)f2bf(x0.w) << 16);
  o.z = (unsigned)f2bf(x1.x) | ((unsigned)f2bf(x1.y) << 16);
  o.w = (unsigned)f2bf(x1.z) | ((unsigned)f2bf(x1.w) << 16);
  ((uint4*)dst)[l] = o;
  #pragma unroll
  for (int off = 32; off > 0; off >>= 1) s += __shfl_down(s, off, 64);
  if (l == 0) {
    if (idx < M_ROWS) {
      nf[idx] = s;
    } else {
      // 32x32 C/D: within-tile row w5 = (r&3) + 8*(r>>2) + 4*h  ->  [tile][h][r]
      int n  = idx - M_ROWS;
      int ig = n >> 5;            // global 32-row tile index (512 tiles)
      int w5 = n & 31;
      int h  = (w5 >> 2) & 1;
      int r  = (w5 & 3) | ((w5 >> 3) << 2);
      nm_perm[(ig * 2 + h) * 16 + r] = s;
    }
  }
}

// ---- Kernel 2: bf16 32x32x16 MFMA GEMM, symmetric 2x2 wave tile, LDS dbuf ----
// grid (64, 8), block 256 (4 waves, wm=w&1, wn=w>>1). Block: 128 m x 2048 n.
// Wave tile: 64 m x 64 n -> acc[2][2] (64 AGPR), 16 b128 frag reads per 16 MFMAs
// (R5 post-mortem: 1x4 tiling burned 20 reads/16 MFMAs; LDS port was top pipe).
// Double-buffered LDS (64 KB), ONE barrier per kc: next tile's global_load_lds
// issued right after the barrier, compute overlaps the loads, next barrier drains
// the remainder. Registers (120 arch + 64 acc = 184) bind us to 2 blocks/CU;
// 64 KB LDS also allows exactly 2 -> dbuf is free occupancy-wise.
// XOR-swizzle unchanged: 16B chunk c of row r at chunk c^(r&7) (R4: -3.0e7 confl).
__global__ __launch_bounds__(256) void gemm_topk_kernel(
    const u16* __restrict__ fvb, const u16* __restrict__ mbb,
    const float* __restrict__ nm_perm, float* __restrict__ partial)
{
  __shared__ __align__(16) u16 As[2][BM * BK];  // fv tiles, 2 x 16 KB
  __shared__ __align__(16) u16 Bs[2][BN * BK];  // mb tiles, 2 x 16 KB

  const int t   = threadIdx.x;
  const int l   = t & 63;
  const int w   = t >> 6;
  const int wm  = w & 1;         // m half (cols)
  const int wn  = w >> 1;        // n half (rows)
  const int h   = l >> 5;        // half-wave
  const int c31 = l & 31;
  const int cx  = c31 & 7;

  const int m0    = blockIdx.x * BM;
  const int ncoff = blockIdx.y * NPER;

  // staging: lane l covers row (base + l>>3), chunk l&7; source chunk swizzled
  const int srow_lo = l >> 3;                    // 0..7
  const int sc      = ((l & 7) ^ srow_lo) * 8;   // swizzled source k-offset (u16)

  float best[2][TOPK];
  float T[2];
  #pragma unroll
  for (int j = 0; j < 2; ++j) {
    T[j] = 3.4e38f;
    #pragma unroll
    for (int i = 0; i < TOPK; ++i) best[j][i] = 3.4e38f;
  }

  // preload tile (nt=0, kc=0) into buffer 0
  {
    const int kb = sc;
    #pragma unroll
    for (int i = 0; i < 4; ++i) {
      gload_lds16(fvb + (size_t)(m0 + w * 32 + i * 8 + srow_lo) * KDIM + kb,
                  &As[0][(w * 32 + i * 8) * BK]);
      gload_lds16(mbb + (size_t)(ncoff + w * 32 + i * 8 + srow_lo) * KDIM + kb,
                  &Bs[0][(w * 32 + i * 8) * BK]);
    }
  }

  for (int nt = 0; nt < NT_CNT; ++nt) {
    const int nbase = ncoff + nt * BN;
    f32x16 acc[2][2];
    #pragma unroll
    for (int i = 0; i < 2; ++i)
      #pragma unroll
      for (int j = 0; j < 2; ++j)
        #pragma unroll
        for (int r = 0; r < 16; ++r) acc[i][j][r] = 0.0f;

    for (int kc = 0; kc < KDIM / BK; ++kc) {
      const int cur = kc & 1;
      __syncthreads();   // buf[cur] staged by all waves (their vmcnt drained here)
      // issue next tile's async loads into buf[cur^1]
      if (kc < KDIM / BK - 1) {
        const int kb = (kc + 1) * BK + sc;
        #pragma unroll
        for (int i = 0; i < 4; ++i) {
          gload_lds16(fvb + (size_t)(m0 + w * 32 + i * 8 + srow_lo) * KDIM + kb,
                      &As[cur ^ 1][(w * 32 + i * 8) * BK]);
          gload_lds16(mbb + (size_t)(nbase + w * 32 + i * 8 + srow_lo) * KDIM + kb,
                      &Bs[cur ^ 1][(w * 32 + i * 8) * BK]);
        }
      } else if (nt + 1 < NT_CNT) {
        const int kb = sc;
        #pragma unroll
        for (int i = 0; i < 4; ++i) {
          gload_lds16(fvb + (size_t)(m0 + w * 32 + i * 8 + srow_lo) * KDIM + kb,
                      &As[cur ^ 1][(w * 32 + i * 8) * BK]);
          gload_lds16(mbb + (size_t)(nbase + BN + w * 32 + i * 8 + srow_lo) * KDIM + kb,
                      &Bs[cur ^ 1][(w * 32 + i * 8) * BK]);
        }
      }
      // compute on buf[cur]
      #pragma unroll
      for (int kk = 0; kk < 4; ++kk) {
        const int ch = ((kk * 2 + h) ^ cx) * 8;              // swizzled chunk (u16)
        bf16x8 fvf0 = *(const bf16x8*)&As[cur][(wm * 64 + c31) * BK + ch];
        bf16x8 fvf1 = *(const bf16x8*)&As[cur][(wm * 64 + 32 + c31) * BK + ch];
        bf16x8 mbf0 = *(const bf16x8*)&Bs[cur][(wn * 64 + c31) * BK + ch];
        bf16x8 mbf1 = *(const bf16x8*)&Bs[cur][(wn * 64 + 32 + c31) * BK + ch];
        acc[0][0] = __builtin_amdgcn_mfma_f32_32x32x16_bf16(mbf0, fvf0, acc[0][0], 0, 0, 0);
        acc[0][1] = __builtin_amdgcn_mfma_f32_32x32x16_bf16(mbf0, fvf1, acc[0][1], 0, 0, 0);
        acc[1][0] = __builtin_amdgcn_mfma_f32_32x32x16_bf16(mbf1, fvf0, acc[1][0], 0, 0, 0);
        acc[1][1] = __builtin_amdgcn_mfma_f32_32x32x16_bf16(mbf1, fvf1, acc[1][1], 0, 0, 0);
      }
    }

    // ---- register epilogue (no LDS, no barrier): 2 lists, 32 n-values each ----
    #pragma unroll
    for (int j = 0; j < 2; ++j) {
      float v[32];
      float bmin = 3.4e38f;
      #pragma unroll
      for (int i = 0; i < 2; ++i) {
        const float4* np =
            (const float4*)&nm_perm[((((nbase >> 5) + wn * 2 + i)) * 2 + h) * 16];
        #pragma unroll
        for (int rr = 0; rr < 4; ++rr) {
          float4 q = np[rr];
          v[i * 16 + rr * 4 + 0] = fmaf(-2.0f, acc[i][j][rr * 4 + 0], q.x);
          v[i * 16 + rr * 4 + 1] = fmaf(-2.0f, acc[i][j][rr * 4 + 1], q.y);
          v[i * 16 + rr * 4 + 2] = fmaf(-2.0f, acc[i][j][rr * 4 + 2], q.z);
          v[i * 16 + rr * 4 + 3] = fmaf(-2.0f, acc[i][j][rr * 4 + 3], q.w);
        }
      }
      #pragma unroll
      for (int r = 0; r < 32; ++r) bmin = fminf(bmin, v[r]);
      if (bmin < T[j]) {
        #pragma unroll
        for (int r = 0; r < 32; ++r) topk_update(v[r], best[j]);
      }
      float th = best[j][TOPK - 1];
      T[j] = fminf(th, __shfl_xor(th, 32, 64));
    }
  }

  // merge the h-pair sharing each m-col (snapshot partner list, then insert)
  #pragma unroll
  for (int j = 0; j < 2; ++j) {
    float tmp[TOPK];
    #pragma unroll
    for (int s = 0; s < TOPK; ++s) tmp[s] = __shfl_xor(best[j][s], 32, 64);
    #pragma unroll
    for (int s = 0; s < TOPK; ++s) topk_update(tmp[s], best[j]);
  }
  // 16 lists per row: (blockIdx.y, wn); h=0 writes 5, h=1 writes 4
  #pragma unroll
  for (int j = 0; j < 2; ++j) {
    int m = m0 + wm * 64 + j * 32 + c31;
    size_t base = ((size_t)(blockIdx.y * 2 + wn) * M_ROWS + m) * TOPK;
    if (h == 0) {
      #pragma unroll
      for (int s = 0; s < 5; ++s) partial[base + s] = best[j][s];
    } else {
      #pragma unroll
      for (int s = 5; s < TOPK; ++s) partial[base + s] = best[j][s];
    }
  }
}

// ---------------- Kernel 3: merge 16 partial lists/row, sqrt, pixel scores ----------------
__global__ __launch_bounds__(256) void merge_kernel(
    const float* __restrict__ partial, const float* __restrict__ nf,
    float* __restrict__ final9, float* __restrict__ out_pix)
{
  int row = blockIdx.x * 256 + threadIdx.x;   // 8192 rows
  float best[TOPK];
  #pragma unroll
  for (int i = 0; i < TOPK; ++i) best[i] = 3.4e38f;
  for (int s = 0; s < 2 * NCHUNKS; ++s) {
    const float* p = &partial[((size_t)s * M_ROWS + row) * TOPK];
    #pragma unroll
    for (int i = 0; i < TOPK; ++i) topk_update(p[i], best);
  }
  float nfr = nf[row];
  float d[TOPK];
  #pragma unroll
  for (int i = 0; i < TOPK; ++i) d[i] = sqrtf(fmaxf(best[i] + nfr, 0.0f));
  out_pix[row] = d[0];
  #pragma unroll
  for (int i = 0; i < TOPK; ++i) final9[(size_t)row * TOPK + i] = d[i];
}

// ---------------- Kernel 4: per-image argmax (first-max) + softmax score ----------------
__global__ __launch_bounds__(256) void img_kernel(
    const float* __restrict__ out_pix, const float* __restrict__ final9,
    const int* __restrict__ bptr, float* __restrict__ out_img)
{
  int img = blockIdx.x, t = threadIdx.x;
  float bv = -1.0f; int bi = 0;
  for (int p = t; p < 1024; p += 256) {
    float v = out_pix[img * 1024 + p];
    if (v > bv) { bv = v; bi = p; }
  }
  __shared__ float sv[256];
  __shared__ int   si[256];
  sv[t] = bv; si[t] = bi;
  __syncthreads();
  for (int off = 128; off > 0; off >>= 1) {
    if (t < off) {
      float v2 = sv[t + off]; int i2 = si[t + off];
      if (v2 > sv[t] || (v2 == sv[t] && i2 < si[t])) { sv[t] = v2; si[t] = i2; }
    }
    __syncthreads();
  }
  if (t == 0) {
    int row = img * 1024 + si[0];
    int b = bptr[0];
    float s0 = final9[(size_t)row * TOPK + 0];
    float score = s0;
    if (b > 1) {
      int bb = b < TOPK ? b : TOPK;
      float mx = s0;
      for (int i = 1; i < bb; ++i) mx = fmaxf(mx, final9[(size_t)row * TOPK + i]);
      float den = 0.0f;
      for (int i = 0; i < bb; ++i) den += expf(final9[(size_t)row * TOPK + i] - mx);
      score = s0 * (1.0f - expf(s0 - mx) / den);
    }
    out_img[img] = score;
  }
}

extern "C" void kernel_launch(void* const* d_in, const int* in_sizes, int n_in,
                              void* d_out, int out_size, void* d_ws, size_t ws_size,
                              hipStream_t stream) {
  const float* fv   = (const float*)d_in[0];
  const float* mb   = (const float*)d_in[1];
  const int*   bptr = (const int*)d_in[2];
  float* out = (float*)d_out;

  char* w = (char*)d_ws;
  u16*   fvb     = (u16*)w;                        // 8388608 B
  u16*   mbb     = (u16*)(w + 8388608);            // 16777216 B
  float* nf      = (float*)(w + 25165824);         // 32768 B
  float* nm_perm = (float*)(w + 25198592);         // 65536 B
  float* partial = (float*)(w + 25264128);         // 16*8192*9*4 = 4718592 B
  float* final9  = (float*)(w + 29982720);         // 294912 B   (end ~30.3 MB)

  hipLaunchKernelGGL(prep_kernel, dim3((M_ROWS + N_ROWS) / 4), dim3(256), 0, stream,
                     fv, mb, fvb, mbb, nf, nm_perm);
  hipLaunchKernelGGL(gemm_topk_kernel, dim3(M_ROWS / BM, NCHUNKS), dim3(256), 0, stream,
                     fvb, mbb, nm_perm, partial);
  hipLaunchKernelGGL(merge_kernel, dim3(M_ROWS / 256), dim3(256), 0, stream,
                     partial, nf, final9, out);
  hipLaunchKernelGGL(img_kernel, dim3(8), dim3(256), 0, stream,
                     out, final9, bptr, out + M_ROWS);
}